// Round 7
// baseline (135.753 us; speedup 1.0000x reference)
//
#include <hip/hip_runtime.h>
#include <math.h>

#define DDIM 256
#define HDIM 64
#define NTOK 1024
#define BDIM 256
#define NCH  16      // chunks per batch (NTOK/64)

typedef __attribute__((ext_vector_type(8))) short short8;
typedef __attribute__((ext_vector_type(4))) float f32x4;

__device__ __forceinline__ ushort f2bf(float f) {   // RNE f32 -> bf16 bits
    uint u = __float_as_uint(f);
    return (ushort)((u + 0x7FFF + ((u >> 16) & 1)) >> 16);
}
__device__ __forceinline__ float bf2f(ushort b) {
    return __uint_as_float(((uint)b) << 16);
}

// Sum over the 16-lane DPP row (lanes kg*16..kg*16+15): ror8, ror4, xor2, xor1.
__device__ __forceinline__ float row_sum16(float v) {
    v += __int_as_float(__builtin_amdgcn_update_dpp(
            0, __float_as_int(v), 0x128, 0xF, 0xF, true));   // row_ror:8
    v += __int_as_float(__builtin_amdgcn_update_dpp(
            0, __float_as_int(v), 0x124, 0xF, 0xF, true));   // row_ror:4
    v += __int_as_float(__builtin_amdgcn_update_dpp(
            0, __float_as_int(v), 0x4E, 0xF, 0xF, true));    // quad_perm [2,3,0,1] = xor2
    v += __int_as_float(__builtin_amdgcn_update_dpp(
            0, __float_as_int(v), 0xB1, 0xF, 0xF, true));    // quad_perm [1,0,3,2] = xor1
    return v;
}

// ---------------- k_pre: c12 + split-bf16 pack of G = gamma ⊙ W1 in MFMA B-fragment order.
// B-frag (16x16x32): lane l holds B[k = (l>>4)*8 + j][n = l&15], j=0..7, contiguous 16B.
// ghi/glo[e], e = ((kt*4+nt)*64 + lane)*8 + j.   (validated R4/R5/R6)
__global__ void k_pre(const float* __restrict__ gamma, const float* __restrict__ beta,
                      const float* __restrict__ W1, const float* __restrict__ b1,
                      float* __restrict__ c12, ushort* __restrict__ ghi,
                      ushort* __restrict__ glo) {
    int tid = threadIdx.x;
    if (blockIdx.x == 0 && tid < HDIM) {
        float s1 = 0.f, s2 = 0.f;
        for (int d = 0; d < DDIM; ++d) {
            float w = W1[d * HDIM + tid];
            s1 = fmaf(gamma[d], w, s1);
            s2 = fmaf(beta[d],  w, s2);
        }
        c12[tid]        = s1;
        c12[HDIM + tid] = s2 + b1[tid];
    }
    int e = blockIdx.x * 256 + tid;            // 64 blocks x 256 = 16384 entries
    int j    = e & 7;
    int lane = (e >> 3) & 63;
    int nt   = (e >> 9) & 3;
    int kt   = e >> 11;
    int k = kt * 32 + (lane >> 4) * 8 + j;
    int n = nt * 16 + (lane & 15);
    float g = gamma[k] * W1[k * HDIM + n];
    ushort hi = f2bf(g);
    ushort lo = f2bf(g - bf2f(hi));
    ghi[e] = hi;
    glo[e] = lo;
}

// ---------------- k_fused v2: one x pass, x kept in REGISTERS end-to-end.
// Phase 1: LN-stats + split-bf16 MFMA logits (validated R5/R6).
// Phase 2: chunk softmax + weighted sum from registers via DPP 16-lane reduce
// (replaces R6's global re-read, which thrashed L2 at ~12-16MB/XCD working set).
__global__ __launch_bounds__(256, 3) void k_fused(
    const float* __restrict__ x, const float* __restrict__ c12,
    const ushort* __restrict__ ghi, const ushort* __restrict__ glo,
    const float* __restrict__ W2, float* __restrict__ logits,
    float* __restrict__ Sc, float2* __restrict__ ml) {
    __shared__ float slog[64];
    __shared__ float Sacc[4][256];
    __shared__ float lsum[4];

    int tid = threadIdx.x, w = tid >> 6, lane = tid & 63;
    int m = lane & 15, kg = lane >> 4;
    size_t tok0 = (size_t)blockIdx.x * 64;          // block's 64 tokens
    size_t wtok = tok0 + (size_t)w * 16;            // wave's 16 tokens

    const float4*  rp  = reinterpret_cast<const float4*>(x + (wtok + m) * DDIM + kg * 8);
    const short8*  gph = reinterpret_cast<const short8*>(ghi);
    const short8*  gpl = reinterpret_cast<const short8*>(glo);

    // Load this lane's 64 x-values (rows m, cols kg*8+{0..7}+32kt) — kept live
    // through phase 2. Static indices -> registers (no scratch).
    float4 xv[16];
    #pragma unroll
    for (int i = 0; i < 16; ++i) xv[i] = rp[(i >> 1) * 8 + (i & 1)];

    // Exact fp32 stats over the lane's 64 elems.
    float s1 = 0.f, s2 = 0.f;
    #pragma unroll
    for (int i = 0; i < 16; ++i) {
        float4 v = xv[i];
        s1 += (v.x + v.y) + (v.z + v.w);
        s2 = fmaf(v.x, v.x, s2); s2 = fmaf(v.y, v.y, s2);
        s2 = fmaf(v.z, v.z, s2); s2 = fmaf(v.w, v.w, s2);
    }

    f32x4 acc[4];
    #pragma unroll
    for (int nt = 0; nt < 4; ++nt) acc[nt] = (f32x4){0.f, 0.f, 0.f, 0.f};

    #pragma unroll
    for (int kt = 0; kt < 8; ++kt) {
        float4 xa = xv[kt * 2];        // k = kt*32 + kg*8 + {0..3}
        float4 xb = xv[kt * 2 + 1];    // k = kt*32 + kg*8 + {4..7}

        uint u0 = __float_as_uint(xa.x), u1 = __float_as_uint(xa.y);
        uint u2 = __float_as_uint(xa.z), u3 = __float_as_uint(xa.w);
        uint u4 = __float_as_uint(xb.x), u5 = __float_as_uint(xb.y);
        uint u6 = __float_as_uint(xb.z), u7 = __float_as_uint(xb.w);

        union { uint4 u; short8 s; } Ah, Al;
        Ah.u.x = (u0 >> 16) | (u1 & 0xFFFF0000u);
        Ah.u.y = (u2 >> 16) | (u3 & 0xFFFF0000u);
        Ah.u.z = (u4 >> 16) | (u5 & 0xFFFF0000u);
        Ah.u.w = (u6 >> 16) | (u7 & 0xFFFF0000u);
        uint r0 = __float_as_uint(xa.x - __uint_as_float(u0 & 0xFFFF0000u));
        uint r1 = __float_as_uint(xa.y - __uint_as_float(u1 & 0xFFFF0000u));
        uint r2 = __float_as_uint(xa.z - __uint_as_float(u2 & 0xFFFF0000u));
        uint r3 = __float_as_uint(xa.w - __uint_as_float(u3 & 0xFFFF0000u));
        uint r4 = __float_as_uint(xb.x - __uint_as_float(u4 & 0xFFFF0000u));
        uint r5 = __float_as_uint(xb.y - __uint_as_float(u5 & 0xFFFF0000u));
        uint r6 = __float_as_uint(xb.z - __uint_as_float(u6 & 0xFFFF0000u));
        uint r7 = __float_as_uint(xb.w - __uint_as_float(u7 & 0xFFFF0000u));
        Al.u.x = (r0 >> 16) | (r1 & 0xFFFF0000u);
        Al.u.y = (r2 >> 16) | (r3 & 0xFFFF0000u);
        Al.u.z = (r4 >> 16) | (r5 & 0xFFFF0000u);
        Al.u.w = (r6 >> 16) | (r7 & 0xFFFF0000u);

        #pragma unroll
        for (int nt = 0; nt < 4; ++nt) {
            short8 bh = gph[(kt * 4 + nt) * 64 + lane];
            short8 bl = gpl[(kt * 4 + nt) * 64 + lane];
            acc[nt] = __builtin_amdgcn_mfma_f32_16x16x32_bf16(Ah.s, bh, acc[nt], 0, 0, 0);
            acc[nt] = __builtin_amdgcn_mfma_f32_16x16x32_bf16(Al.s, bh, acc[nt], 0, 0, 0);
            acc[nt] = __builtin_amdgcn_mfma_f32_16x16x32_bf16(Ah.s, bl, acc[nt], 0, 0, 0);
        }
    }

    // Row stats: union over the 4 kg-groups = full row; reduce across kg.
    s1 += __shfl_xor(s1, 16); s1 += __shfl_xor(s1, 32);
    s2 += __shfl_xor(s2, 16); s2 += __shfl_xor(s2, 32);
    float mu  = s1 * (1.f / DDIM);
    float var = fmaf(-mu, mu, s2 * (1.f / DDIM));
    float sv  = rsqrtf(var + 1e-5f);

    // Epilogue: LN fixup + exact GELU + W2 dot; logits -> LDS + global.
    float c1v[4], c2v[4], w2v[4];
    #pragma unroll
    for (int nt = 0; nt < 4; ++nt) {
        c1v[nt] = c12[nt * 16 + m];
        c2v[nt] = c12[HDIM + nt * 16 + m];
        w2v[nt] = W2[nt * 16 + m];
    }
    #pragma unroll
    for (int r = 0; r < 4; ++r) {
        int row = kg * 4 + r;
        float mur = __shfl(mu, row);
        float svr = __shfl(sv, row);
        float v = 0.f;
        #pragma unroll
        for (int nt = 0; nt < 4; ++nt) {
            float pre = fmaf(svr, fmaf(-mur, c1v[nt], acc[nt][r]), c2v[nt]);
            float g   = 0.5f * pre * (1.f + erff(pre * 0.70710678118654752f));
            v = fmaf(g, w2v[nt], v);
        }
        v += __shfl_xor(v, 1); v += __shfl_xor(v, 2);
        v += __shfl_xor(v, 4); v += __shfl_xor(v, 8);
        if (m == 0) {
            slog[w * 16 + row]  = v;
            logits[wtok + row]  = v;
        }
    }
    __syncthreads();

    // ---- Phase 2: chunk softmax + weighted sum straight from registers.
    const float4* sl4 = reinterpret_cast<const float4*>(slog);
    float mc = -1e30f;
    #pragma unroll
    for (int i = 0; i < 16; ++i) {
        float4 q = sl4[i];
        mc = fmaxf(mc, fmaxf(fmaxf(q.x, q.y), fmaxf(q.z, q.w)));
    }
    float p  = __expf(slog[w * 16 + m] - mc);    // this lane's row weight
    float lw = row_sum16(p);
    if (lane == 0) lsum[w] = lw;

    bool writer = (m == 0);
    #pragma unroll
    for (int i = 0; i < 16; ++i) {
        float4 svv;
        svv.x = row_sum16(p * xv[i].x);
        svv.y = row_sum16(p * xv[i].y);
        svv.z = row_sum16(p * xv[i].z);
        svv.w = row_sum16(p * xv[i].w);
        if (writer)
            *reinterpret_cast<float4*>(&Sacc[w][(i >> 1) * 32 + kg * 8 + (i & 1) * 4]) = svv;
    }
    __syncthreads();

    if (w == 0) {
        float4 q0 = *reinterpret_cast<const float4*>(&Sacc[0][lane * 4]);
        float4 q1 = *reinterpret_cast<const float4*>(&Sacc[1][lane * 4]);
        float4 q2 = *reinterpret_cast<const float4*>(&Sacc[2][lane * 4]);
        float4 q3 = *reinterpret_cast<const float4*>(&Sacc[3][lane * 4]);
        float4 S;
        S.x = (q0.x + q1.x) + (q2.x + q3.x);
        S.y = (q0.y + q1.y) + (q2.y + q3.y);
        S.z = (q0.z + q1.z) + (q2.z + q3.z);
        S.w = (q0.w + q1.w) + (q2.w + q3.w);
        reinterpret_cast<float4*>(Sc + (size_t)blockIdx.x * DDIM)[lane] = S;
        if (lane == 0)
            ml[blockIdx.x] = make_float2(mc, (lsum[0] + lsum[1]) + (lsum[2] + lsum[3]));
    }
}

// ---------------- k_combine: per batch, merge 16 chunks -> summary + weights.
// summary[b,d] = sum_c e^{m_c-M} Sc[c,d] / denom;  weights[n] = e^{logit_n - M}/denom.
__global__ __launch_bounds__(256) void k_combine(
    const float* __restrict__ Sc, const float2* __restrict__ ml,
    float* __restrict__ summary, float* __restrict__ wts) {
    int b = blockIdx.x, tid = threadIdx.x;

    float2 mlv[NCH];
    float M = -1e30f;
    #pragma unroll
    for (int c = 0; c < NCH; ++c) { mlv[c] = ml[b * NCH + c]; M = fmaxf(M, mlv[c].x); }
    float ex[NCH];
    float denom = 0.f;
    #pragma unroll
    for (int c = 0; c < NCH; ++c) {
        ex[c] = __expf(mlv[c].x - M);
        denom = fmaf(ex[c], mlv[c].y, denom);
    }
    float inv = 1.f / denom;

    float s = 0.f;
    #pragma unroll
    for (int c = 0; c < NCH; ++c)
        s = fmaf(ex[c], Sc[((size_t)b * NCH + c) * DDIM + tid], s);
    summary[(size_t)b * DDIM + tid] = s * inv;

    // weights: 4 tokens per thread, in-place over staged logits.
    float4* wp = reinterpret_cast<float4*>(wts + (size_t)b * NTOK) + tid;
    float4 lg = *wp;
    lg.x = __expf(lg.x - M) * inv;
    lg.y = __expf(lg.y - M) * inv;
    lg.z = __expf(lg.z - M) * inv;
    lg.w = __expf(lg.w - M) * inv;
    *wp = lg;
}

extern "C" void kernel_launch(void* const* d_in, const int* in_sizes, int n_in,
                              void* d_out, int out_size, void* d_ws, size_t ws_size,
                              hipStream_t stream) {
    const float* x     = (const float*)d_in[0];
    const float* gamma = (const float*)d_in[1];
    const float* beta  = (const float*)d_in[2];
    const float* W1    = (const float*)d_in[3];
    const float* b1    = (const float*)d_in[4];
    const float* W2    = (const float*)d_in[5];
    // d_in[6] = b2: softmax-invariant, unused.

    float* out     = (float*)d_out;
    float* summary = out;                       // B*D
    float* wts     = out + (size_t)BDIM * DDIM; // B*N (logits staged, then weights)

    // ws layout: c12 (512B) | ghi (32KB) | glo (32KB) | Sc (4MB) | ml (32KB)
    float*  c12 = (float*)d_ws;
    ushort* ghi = (ushort*)((char*)d_ws + 512);
    ushort* glo = ghi + 16384;
    float*  Sc  = (float*)((char*)d_ws + 512 + 65536);
    float2* ml  = (float2*)((char*)d_ws + 512 + 65536 +
                            (size_t)BDIM * NCH * DDIM * sizeof(float));

    hipLaunchKernelGGL(k_pre, dim3(64), dim3(256), 0, stream,
                       gamma, beta, W1, b1, c12, ghi, glo);
    hipLaunchKernelGGL(k_fused, dim3(BDIM * NCH), dim3(256), 0, stream,
                       x, c12, ghi, glo, W2, wts, Sc, ml);
    hipLaunchKernelGGL(k_combine, dim3(BDIM), dim3(256), 0, stream,
                       Sc, ml, summary, wts);
}

// Round 8
// 111.589 us; speedup vs baseline: 1.2165x; 1.2165x over previous
//
#include <hip/hip_runtime.h>
#include <math.h>

#define DDIM 256
#define HDIM 64
#define NTOK 1024
#define BDIM 256
#define NCH  16      // chunks per batch (NTOK/64)

typedef __attribute__((ext_vector_type(8))) short short8;
typedef __attribute__((ext_vector_type(4))) float f32x4;

__device__ __forceinline__ ushort f2bf(float f) {   // RNE f32 -> bf16 bits
    uint u = __float_as_uint(f);
    return (ushort)((u + 0x7FFF + ((u >> 16) & 1)) >> 16);
}
__device__ __forceinline__ float bf2f(ushort b) {
    return __uint_as_float(((uint)b) << 16);
}

// Abramowitz-Stegun 7.1.26 erf, |err| <= 1.5e-7 — far cheaper than libm erff.
__device__ __forceinline__ float erf_fast(float x) {
    float ax = fabsf(x);
    float t  = __builtin_amdgcn_rcpf(fmaf(0.3275911f, ax, 1.0f));
    float e  = __expf(-ax * ax);
    float p  = t * fmaf(t, fmaf(t, fmaf(t, fmaf(t, 1.061405429f, -1.453152027f),
                                        1.421413741f), -0.284496736f), 0.254829592f);
    float r  = fmaf(-p, e, 1.0f);
    return copysignf(r, x);
}

// ---------------- k_pre: c12 + split-bf16 pack of G = gamma ⊙ W1 in MFMA B-fragment order.
// B-frag (16x16x32): lane l holds B[k = (l>>4)*8 + j][n = l&15], j=0..7, contiguous 16B.
// ghi/glo[e], e = ((kt*4+nt)*64 + lane)*8 + j.   (validated R4-R7)
__global__ void k_pre(const float* __restrict__ gamma, const float* __restrict__ beta,
                      const float* __restrict__ W1, const float* __restrict__ b1,
                      float* __restrict__ c12, ushort* __restrict__ ghi,
                      ushort* __restrict__ glo) {
    int tid = threadIdx.x;
    if (blockIdx.x == 0 && tid < HDIM) {
        float s1 = 0.f, s2 = 0.f;
        for (int d = 0; d < DDIM; ++d) {
            float w = W1[d * HDIM + tid];
            s1 = fmaf(gamma[d], w, s1);
            s2 = fmaf(beta[d],  w, s2);
        }
        c12[tid]        = s1;
        c12[HDIM + tid] = s2 + b1[tid];
    }
    int e = blockIdx.x * 256 + tid;            // 64 blocks x 256 = 16384 entries
    int j    = e & 7;
    int lane = (e >> 3) & 63;
    int nt   = (e >> 9) & 3;
    int kt   = e >> 11;
    int k = kt * 32 + (lane >> 4) * 8 + j;
    int n = nt * 16 + (lane & 15);
    float g = gamma[k] * W1[k * HDIM + n];
    ushort hi = f2bf(g);
    ushort lo = f2bf(g - bf2f(hi));
    ghi[e] = hi;
    glo[e] = lo;
}

// ---------------- k_fused (R6 structure + batched loads + prefetch + fast erf).
// Phase 1: LN-stats + split-bf16 MFMA logits. Phase 2: chunk softmax + weighted
// sum re-reading the tile (prefetched before the epilogue so L3 latency hides
// under the erf/W2 work). No long-lived x registers across MFMA (R7 lesson).
__global__ __launch_bounds__(256) void k_fused(
    const float* __restrict__ x, const float* __restrict__ c12,
    const ushort* __restrict__ ghi, const ushort* __restrict__ glo,
    const float* __restrict__ W2, float* __restrict__ logits,
    float* __restrict__ Sc, float2* __restrict__ ml) {
    __shared__ float  slog[64];
    __shared__ float4 Sw[4][64];
    __shared__ float  lsum[4];

    int tid = threadIdx.x, w = tid >> 6, lane = tid & 63;
    int m = lane & 15, kg = lane >> 4;
    size_t tok0 = (size_t)blockIdx.x * 64;          // block's 64 tokens
    size_t wtok = tok0 + (size_t)w * 16;            // wave's 16 tokens

    const float4*  rp  = reinterpret_cast<const float4*>(x + (wtok + m) * DDIM + kg * 8);
    const short8*  gph = reinterpret_cast<const short8*>(ghi);
    const short8*  gpl = reinterpret_cast<const short8*>(glo);

    f32x4 acc[4];
    #pragma unroll
    for (int nt = 0; nt < 4; ++nt) acc[nt] = (f32x4){0.f, 0.f, 0.f, 0.f};

    float s1 = 0.f, s2 = 0.f;

    // ---- Phase 1 in two half-batches: 8 float4 loads issued together (one
    // latency exposure per half), consumed immediately (registers die in-half).
    #pragma unroll
    for (int half = 0; half < 2; ++half) {
        float4 xv[8];
        #pragma unroll
        for (int i = 0; i < 8; ++i)
            xv[i] = rp[(half * 4 + (i >> 1)) * 8 + (i & 1)];

        #pragma unroll
        for (int kk = 0; kk < 4; ++kk) {
            int kt = half * 4 + kk;
            float4 xa = xv[kk * 2];        // k = kt*32 + kg*8 + {0..3}
            float4 xb = xv[kk * 2 + 1];    // k = kt*32 + kg*8 + {4..7}

            s1 += ((xa.x + xa.y) + (xa.z + xa.w)) + ((xb.x + xb.y) + (xb.z + xb.w));
            s2 = fmaf(xa.x, xa.x, s2); s2 = fmaf(xa.y, xa.y, s2);
            s2 = fmaf(xa.z, xa.z, s2); s2 = fmaf(xa.w, xa.w, s2);
            s2 = fmaf(xb.x, xb.x, s2); s2 = fmaf(xb.y, xb.y, s2);
            s2 = fmaf(xb.z, xb.z, s2); s2 = fmaf(xb.w, xb.w, s2);

            uint u0 = __float_as_uint(xa.x), u1 = __float_as_uint(xa.y);
            uint u2 = __float_as_uint(xa.z), u3 = __float_as_uint(xa.w);
            uint u4 = __float_as_uint(xb.x), u5 = __float_as_uint(xb.y);
            uint u6 = __float_as_uint(xb.z), u7 = __float_as_uint(xb.w);

            union { uint4 u; short8 s; } Ah, Al;
            Ah.u.x = (u0 >> 16) | (u1 & 0xFFFF0000u);
            Ah.u.y = (u2 >> 16) | (u3 & 0xFFFF0000u);
            Ah.u.z = (u4 >> 16) | (u5 & 0xFFFF0000u);
            Ah.u.w = (u6 >> 16) | (u7 & 0xFFFF0000u);
            uint r0 = __float_as_uint(xa.x - __uint_as_float(u0 & 0xFFFF0000u));
            uint r1 = __float_as_uint(xa.y - __uint_as_float(u1 & 0xFFFF0000u));
            uint r2 = __float_as_uint(xa.z - __uint_as_float(u2 & 0xFFFF0000u));
            uint r3 = __float_as_uint(xa.w - __uint_as_float(u3 & 0xFFFF0000u));
            uint r4 = __float_as_uint(xb.x - __uint_as_float(u4 & 0xFFFF0000u));
            uint r5 = __float_as_uint(xb.y - __uint_as_float(u5 & 0xFFFF0000u));
            uint r6 = __float_as_uint(xb.z - __uint_as_float(u6 & 0xFFFF0000u));
            uint r7 = __float_as_uint(xb.w - __uint_as_float(u7 & 0xFFFF0000u));
            Al.u.x = (r0 >> 16) | (r1 & 0xFFFF0000u);
            Al.u.y = (r2 >> 16) | (r3 & 0xFFFF0000u);
            Al.u.z = (r4 >> 16) | (r5 & 0xFFFF0000u);
            Al.u.w = (r6 >> 16) | (r7 & 0xFFFF0000u);

            #pragma unroll
            for (int nt = 0; nt < 4; ++nt) {
                short8 bh = gph[(kt * 4 + nt) * 64 + lane];
                short8 bl = gpl[(kt * 4 + nt) * 64 + lane];
                acc[nt] = __builtin_amdgcn_mfma_f32_16x16x32_bf16(Ah.s, bh, acc[nt], 0, 0, 0);
                acc[nt] = __builtin_amdgcn_mfma_f32_16x16x32_bf16(Al.s, bh, acc[nt], 0, 0, 0);
                acc[nt] = __builtin_amdgcn_mfma_f32_16x16x32_bf16(Ah.s, bl, acc[nt], 0, 0, 0);
            }
        }
    }

    // ---- Prefetch phase-2 re-read NOW: 16 coalesced float4 rows; latency hides
    // under the stats-reduce + erf epilogue below. (xv/temps are dead here.)
    float4 xr[16];
    const float* xb0 = x + wtok * DDIM;
    #pragma unroll
    for (int r = 0; r < 16; ++r)
        xr[r] = *reinterpret_cast<const float4*>(xb0 + (size_t)r * DDIM + lane * 4);

    // Row stats: union over the 4 kg-groups = full row; reduce across kg.
    s1 += __shfl_xor(s1, 16); s1 += __shfl_xor(s1, 32);
    s2 += __shfl_xor(s2, 16); s2 += __shfl_xor(s2, 32);
    float mu  = s1 * (1.f / DDIM);
    float var = fmaf(-mu, mu, s2 * (1.f / DDIM));
    float sv  = rsqrtf(var + 1e-5f);

    // Epilogue: LN fixup + fast-erf GELU + W2 dot; logits -> LDS + global.
    float c1v[4], c2v[4], w2v[4];
    #pragma unroll
    for (int nt = 0; nt < 4; ++nt) {
        c1v[nt] = c12[nt * 16 + m];
        c2v[nt] = c12[HDIM + nt * 16 + m];
        w2v[nt] = W2[nt * 16 + m];
    }
    #pragma unroll
    for (int r = 0; r < 4; ++r) {
        int row = kg * 4 + r;
        float mur = __shfl(mu, row);
        float svr = __shfl(sv, row);
        float v = 0.f;
        #pragma unroll
        for (int nt = 0; nt < 4; ++nt) {
            float pre = fmaf(svr, fmaf(-mur, c1v[nt], acc[nt][r]), c2v[nt]);
            float g   = 0.5f * pre * (1.f + erf_fast(pre * 0.70710678118654752f));
            v = fmaf(g, w2v[nt], v);
        }
        v += __shfl_xor(v, 1); v += __shfl_xor(v, 2);
        v += __shfl_xor(v, 4); v += __shfl_xor(v, 8);
        if (m == 0) {
            slog[w * 16 + row]  = v;
            logits[wtok + row]  = v;
        }
    }
    __syncthreads();

    // ---- Phase 2: chunk softmax + weighted sum from the prefetched tile.
    const float4* sl4 = reinterpret_cast<const float4*>(slog);
    float mc = -1e30f;
    #pragma unroll
    for (int i = 0; i < 16; ++i) {
        float4 q = sl4[i];
        mc = fmaxf(mc, fmaxf(fmaxf(q.x, q.y), fmaxf(q.z, q.w)));
    }

    float4 a4 = {0.f, 0.f, 0.f, 0.f};
    float lw = 0.f;
    #pragma unroll
    for (int r = 0; r < 16; ++r) {
        float p = __expf(slog[w * 16 + r] - mc);
        lw += p;
        a4.x = fmaf(p, xr[r].x, a4.x); a4.y = fmaf(p, xr[r].y, a4.y);
        a4.z = fmaf(p, xr[r].z, a4.z); a4.w = fmaf(p, xr[r].w, a4.w);
    }
    Sw[w][lane] = a4;
    if (lane == 0) lsum[w] = lw;
    __syncthreads();

    if (w == 0) {
        float4 q0 = Sw[0][lane], q1 = Sw[1][lane], q2 = Sw[2][lane], q3 = Sw[3][lane];
        float4 S;
        S.x = (q0.x + q1.x) + (q2.x + q3.x);
        S.y = (q0.y + q1.y) + (q2.y + q3.y);
        S.z = (q0.z + q1.z) + (q2.z + q3.z);
        S.w = (q0.w + q1.w) + (q2.w + q3.w);
        reinterpret_cast<float4*>(Sc + (size_t)blockIdx.x * DDIM)[lane] = S;
        if (lane == 0)
            ml[blockIdx.x] = make_float2(mc, (lsum[0] + lsum[1]) + (lsum[2] + lsum[3]));
    }
}

// ---------------- k_combine: per batch, merge 16 chunks -> summary + weights.
// summary[b,d] = sum_c e^{m_c-M} Sc[c,d] / denom;  weights[n] = e^{logit_n - M}/denom.
__global__ __launch_bounds__(256) void k_combine(
    const float* __restrict__ Sc, const float2* __restrict__ ml,
    float* __restrict__ summary, float* __restrict__ wts) {
    int b = blockIdx.x, tid = threadIdx.x;

    float2 mlv[NCH];
    float M = -1e30f;
    #pragma unroll
    for (int c = 0; c < NCH; ++c) { mlv[c] = ml[b * NCH + c]; M = fmaxf(M, mlv[c].x); }
    float ex[NCH];
    float denom = 0.f;
    #pragma unroll
    for (int c = 0; c < NCH; ++c) {
        ex[c] = __expf(mlv[c].x - M);
        denom = fmaf(ex[c], mlv[c].y, denom);
    }
    float inv = 1.f / denom;

    float s = 0.f;
    #pragma unroll
    for (int c = 0; c < NCH; ++c)
        s = fmaf(ex[c], Sc[((size_t)b * NCH + c) * DDIM + tid], s);
    summary[(size_t)b * DDIM + tid] = s * inv;

    // weights: 4 tokens per thread, in-place over staged logits.
    float4* wp = reinterpret_cast<float4*>(wts + (size_t)b * NTOK) + tid;
    float4 lg = *wp;
    lg.x = __expf(lg.x - M) * inv;
    lg.y = __expf(lg.y - M) * inv;
    lg.z = __expf(lg.z - M) * inv;
    lg.w = __expf(lg.w - M) * inv;
    *wp = lg;
}

extern "C" void kernel_launch(void* const* d_in, const int* in_sizes, int n_in,
                              void* d_out, int out_size, void* d_ws, size_t ws_size,
                              hipStream_t stream) {
    const float* x     = (const float*)d_in[0];
    const float* gamma = (const float*)d_in[1];
    const float* beta  = (const float*)d_in[2];
    const float* W1    = (const float*)d_in[3];
    const float* b1    = (const float*)d_in[4];
    const float* W2    = (const float*)d_in[5];
    // d_in[6] = b2: softmax-invariant, unused.

    float* out     = (float*)d_out;
    float* summary = out;                       // B*D
    float* wts     = out + (size_t)BDIM * DDIM; // B*N (logits staged, then weights)

    // ws layout: c12 (512B) | ghi (32KB) | glo (32KB) | Sc (4MB) | ml (32KB)
    float*  c12 = (float*)d_ws;
    ushort* ghi = (ushort*)((char*)d_ws + 512);
    ushort* glo = ghi + 16384;
    float*  Sc  = (float*)((char*)d_ws + 512 + 65536);
    float2* ml  = (float2*)((char*)d_ws + 512 + 65536 +
                            (size_t)BDIM * NCH * DDIM * sizeof(float));

    hipLaunchKernelGGL(k_pre, dim3(64), dim3(256), 0, stream,
                       gamma, beta, W1, b1, c12, ghi, glo);
    hipLaunchKernelGGL(k_fused, dim3(BDIM * NCH), dim3(256), 0, stream,
                       x, c12, ghi, glo, W2, wts, Sc, ml);
    hipLaunchKernelGGL(k_combine, dim3(BDIM), dim3(256), 0, stream,
                       Sc, ml, summary, wts);
}